// Round 3
// baseline (4657.648 us; speedup 1.0000x reference)
//
#include <hip/hip_runtime.h>
#include <hip/hip_bf16.h>
#include <hip/hip_fp16.h>

typedef unsigned short u16;
typedef unsigned int u32;
typedef __attribute__((ext_vector_type(8))) short bf16x8;
typedef __attribute__((ext_vector_type(4))) float f32x4;
typedef _Float16 __attribute__((ext_vector_type(2))) f16x2;

#define MFMA16(a, b, c) __builtin_amdgcn_mfma_f32_16x16x32_bf16((a), (b), (c), 0, 0, 0)

__device__ __forceinline__ float bflo(u32 u) { return __uint_as_float(u << 16); }
__device__ __forceinline__ float bfhi(u32 u) { return __uint_as_float(u & 0xffff0000u); }
__device__ __forceinline__ float bf1(u16 u) { return __uint_as_float(((u32)u) << 16); }
__device__ __forceinline__ u16 f2bf(float f) {
    __hip_bfloat16 b = __float2bfloat16(f);
    return __builtin_bit_cast(u16, b);
}

// ---------------------------------------------------------------------------
// Wave-uniform on-device dtype sniff: 1 = inputs are fp32, 0 = bf16.
// Interpret first 256B of W_r as bf16. True bf16 weights: |w| < 1.
// fp32 misread as bf16: low halves are mantissa bits -> huge/NaN bf16 with
// P ~ 1 - 1e-17 over 64 samples. Deterministic -> graph-safe.
// ---------------------------------------------------------------------------
__device__ __forceinline__ int sniff_fp32(const void* Wr) {
    const uint4* p = (const uint4*)Wr;
    uint4 v = p[threadIdx.x & 15];
    u32 a[4] = {v.x, v.y, v.z, v.w};
    float m = 0.f;
#pragma unroll
    for (int i = 0; i < 4; ++i) {
        float lo = fabsf(bflo(a[i])), hi = fabsf(bfhi(a[i]));
        if (!(lo < 1e30f)) lo = 1e30f;   // NaN/Inf -> huge
        if (!(hi < 1e30f)) hi = 1e30f;
        m = fmaxf(m, fmaxf(lo, hi));
    }
#pragma unroll
    for (int off = 32; off; off >>= 1) m = fmaxf(m, __shfl_xor(m, off, 64));
    return m > 100.f ? 1 : 0;
}

// 8 consecutive elements at element-index idx -> bf16x8 (for MFMA frags)
__device__ __forceinline__ bf16x8 load8bf(const void* base, size_t idx, int f32) {
    if (f32) {
        const float4* p = (const float4*)((const float*)base + idx);
        float4 v0 = p[0], v1 = p[1];
        bf16x8 r;
        r[0] = (short)f2bf(v0.x); r[1] = (short)f2bf(v0.y);
        r[2] = (short)f2bf(v0.z); r[3] = (short)f2bf(v0.w);
        r[4] = (short)f2bf(v1.x); r[5] = (short)f2bf(v1.y);
        r[6] = (short)f2bf(v1.z); r[7] = (short)f2bf(v1.w);
        return r;
    }
    return *(const bf16x8*)((const u16*)base + idx);
}

// 8 consecutive elements -> 4 fp16 pairs (for the scan's register weights)
__device__ __forceinline__ void load8h(const void* base, size_t idx, int f32, f16x2* dst) {
    if (f32) {
        const float4* p = (const float4*)((const float*)base + idx);
        float4 v0 = p[0], v1 = p[1];
        dst[0] = f16x2{(_Float16)v0.x, (_Float16)v0.y};
        dst[1] = f16x2{(_Float16)v0.z, (_Float16)v0.w};
        dst[2] = f16x2{(_Float16)v1.x, (_Float16)v1.y};
        dst[3] = f16x2{(_Float16)v1.z, (_Float16)v1.w};
    } else {
        uint4 v = *(const uint4*)((const u16*)base + idx);
        dst[0] = f16x2{(_Float16)bflo(v.x), (_Float16)bfhi(v.x)};
        dst[1] = f16x2{(_Float16)bflo(v.y), (_Float16)bfhi(v.y)};
        dst[2] = f16x2{(_Float16)bflo(v.z), (_Float16)bfhi(v.z)};
        dst[3] = f16x2{(_Float16)bflo(v.w), (_Float16)bfhi(v.w)};
    }
}

__device__ __forceinline__ float load1f(const void* base, size_t idx, int f32) {
    return f32 ? ((const float*)base)[idx] : bf1(((const u16*)base)[idx]);
}

// ---------------------------------------------------------------------------
// Precompute: gx[b][sl][g][n] = x_t . W_g[n][0:256] + b_g[n]  (stored fp16)
// GEMM [64*Sc, 256] x [256, 768], MFMA 16x16x32 bf16.
// ---------------------------------------------------------------------------
__global__ __launch_bounds__(256) void gru_pre(
    const void* __restrict__ x,
    const void* __restrict__ Wr, const void* __restrict__ Wz, const void* __restrict__ Wh,
    const void* __restrict__ br, const void* __restrict__ bz, const void* __restrict__ bh,
    __half* __restrict__ gxc, int s0, int lgSc)
{
    const int f32 = sniff_fp32(Wr);
    const int lane = threadIdx.x & 63;
    const int wave = threadIdx.x >> 6;
    const int q = lane >> 4, l16 = lane & 15;
    const int m0 = blockIdx.x * 64 + wave * 16;
    const int by = blockIdx.y;                    // 12 col-groups of 64
    const int g = by >> 2;
    const int out0 = (by & 3) * 64;
    const void* W    = (g == 0) ? Wr : ((g == 1) ? Wz : Wh);
    const void* bias = (g == 0) ? br : ((g == 1) ? bz : bh);
    const int Sc = 1 << lgSc;

    // A: m = lane&15, k = quad*8 + j  (within each K=32 window)
    const int mA = m0 + l16;
    const int bA = mA >> lgSc;
    const int slA = mA & (Sc - 1);
    const size_t aidx = ((size_t)(bA * 2048 + s0 + slA)) * 256 + q * 8;
    // B: n = lane&15 supplies W[out0+t*16+l16][k], k = quad*8 + j
    const size_t widx = (size_t)(out0 + l16) * 512 + q * 8;

    f32x4 acc[4] = {{0,0,0,0},{0,0,0,0},{0,0,0,0},{0,0,0,0}};
#pragma unroll
    for (int k0 = 0; k0 < 256; k0 += 32) {
        bf16x8 af = load8bf(x, aidx + k0, f32);
#pragma unroll
        for (int t = 0; t < 4; ++t) {
            bf16x8 bfg = load8bf(W, widx + (size_t)t * 16 * 512 + k0, f32);
            acc[t] = MFMA16(af, bfg, acc[t]);
        }
    }
    // D: col = lane&15, row = quad*4 + reg
#pragma unroll
    for (int t = 0; t < 4; ++t) {
        const int col = out0 + t * 16 + l16;
        const float bv = load1f(bias, col, f32);
#pragma unroll
        for (int r = 0; r < 4; ++r) {
            const int row = m0 + q * 4 + r;       // == b*Sc + sl
            gxc[(size_t)row * 768 + g * 256 + col] = __float2half(acc[t][r] + bv);
        }
    }
}

// ---------------------------------------------------------------------------
// 256-wide dot: fp16 pairs, fp32 accumulate (v_dot2_f32_f16). w in registers,
// hp in LDS (same-address wave broadcast, conflict-free).
// ---------------------------------------------------------------------------
__device__ __forceinline__ float dot256(const f16x2* w, const _Float16* hp) {
    const uint4* hp4 = (const uint4*)hp;
    float a0 = 0.f, a1 = 0.f, a2 = 0.f, a3 = 0.f;
#pragma unroll
    for (int c = 0; c < 32; ++c) {
        uint4 hv = hp4[c];
        f16x2 h0 = __builtin_bit_cast(f16x2, hv.x);
        f16x2 h1 = __builtin_bit_cast(f16x2, hv.y);
        f16x2 h2 = __builtin_bit_cast(f16x2, hv.z);
        f16x2 h3 = __builtin_bit_cast(f16x2, hv.w);
#if __has_builtin(__builtin_amdgcn_fdot2)
        a0 = __builtin_amdgcn_fdot2(w[c * 4 + 0], h0, a0, false);
        a1 = __builtin_amdgcn_fdot2(w[c * 4 + 1], h1, a1, false);
        a2 = __builtin_amdgcn_fdot2(w[c * 4 + 2], h2, a2, false);
        a3 = __builtin_amdgcn_fdot2(w[c * 4 + 3], h3, a3, false);
#else
        a0 += (float)w[c*4+0][0] * (float)h0[0] + (float)w[c*4+0][1] * (float)h0[1];
        a1 += (float)w[c*4+1][0] * (float)h1[0] + (float)w[c*4+1][1] * (float)h1[1];
        a2 += (float)w[c*4+2][0] * (float)h2[0] + (float)w[c*4+2][1] * (float)h2[1];
        a3 += (float)w[c*4+3][0] * (float)h3[0] + (float)w[c*4+3][1] * (float)h3[1];
#endif
    }
    return (a0 + a1) + (a2 + a3);
}

// ---------------------------------------------------------------------------
// Sequential scan: one workgroup per batch element, 768 threads.
// Thread (g = tid>>8, n = tid&255) owns W_g[n][256:512] in 128 f16x2 regs.
// h recurrence in fp32; hs written to d_out in the OUTPUT dtype.
// ---------------------------------------------------------------------------
__global__ __launch_bounds__(768) void gru_scan(
    const __half* __restrict__ gxc,
    const void* __restrict__ Wr, const void* __restrict__ Wz, const void* __restrict__ Wh,
    float* __restrict__ h_state,
    void* __restrict__ outbase,            // d_out: hs[b][s][n] + h_last at elt 33554432
    int s0, int Sc, int first, int last)
{
    const int f32 = sniff_fp32(Wr);
    const int b = blockIdx.x;
    const int tid = threadIdx.x;
    const int g = tid >> 8;   // 0=r, 1=z, 2=h  (wave-uniform)
    const int n = tid & 255;

    __shared__ __align__(16) _Float16 h_h[256];   // h as fp16 (dot input)
    __shared__ __align__(16) _Float16 rh_h[256];  // r*h as fp16 (dot input)
    __shared__ float h_f[256];                    // h fp32 (exact recurrence)
    __shared__ float z_f[256];

    // Preload my weight row W_g[n][256:512] (-> fp16, exact in this range)
    const void* W = (g == 0) ? Wr : ((g == 1) ? Wz : Wh);
    f16x2 w[128];
#pragma unroll
    for (int c = 0; c < 32; ++c)
        load8h(W, (size_t)n * 512 + 256 + c * 8, f32, &w[c * 4]);

    if (g == 0) {
        float h0 = first ? 0.0f : h_state[b * 256 + n];
        h_f[n] = h0;
        h_h[n] = (_Float16)h0;
    }
    __syncthreads();

    const __half* gxp = gxc + (size_t)b * Sc * 768 + g * 256 + n;
    __half cur = gxp[0];

    for (int s = 0; s < Sc; ++s) {
        __half nxt = (s + 1 < Sc) ? gxp[(size_t)(s + 1) * 768] : cur;  // prefetch

        if (g < 2) {  // phase 1: r and z gates
            float acc = dot256(w, h_h);
            float pre = acc + __half2float(cur);
            pre = fminf(fmaxf(pre, -30.0f), 30.0f);
            float val = __fdividef(1.0f, 1.0f + __expf(-pre));
            if (g == 0) rh_h[n] = (_Float16)(val * h_f[n]);
            else        z_f[n] = val;
        }
        __syncthreads();

        if (g == 2) {  // phase 2: candidate + update
            float acc = dot256(w, rh_h);
            float pre = acc + __half2float(cur);
            pre = fminf(fmaxf(pre, -15.0f), 15.0f);
            float e = __expf(2.0f * pre);
            float ht = __fdividef(e - 1.0f, e + 1.0f);   // tanh
            float hold = h_f[n];
            float zz = z_f[n];
            float hn = hold + zz * (ht - hold);          // (1-z)h + z*ht
            h_f[n] = hn;
            h_h[n] = (_Float16)hn;
            const size_t oidx = (size_t)(b * 2048 + s0 + s) * 256 + n;
            if (f32) ((float*)outbase)[oidx] = hn;
            else     ((u16*)outbase)[oidx] = f2bf(hn);
            if (s == Sc - 1) {
                h_state[b * 256 + n] = hn;
                if (last) {
                    const size_t lidx = (size_t)33554432 + b * 256 + n;
                    if (f32) ((float*)outbase)[lidx] = hn;
                    else     ((u16*)outbase)[lidx] = f2bf(hn);
                }
            }
        }
        __syncthreads();
        cur = nxt;
    }
}

// ---------------------------------------------------------------------------
// Output projection IN-PLACE in d_out: out[row][o] = hs[row][:] . W_fc[o][:]
// + b_fc[o]. Each wave reads exactly the 16 rows it later overwrites (all
// loads precede all stores in program order; waves/blocks own disjoint rows).
// ---------------------------------------------------------------------------
__global__ __launch_bounds__(256) void gru_proj(
    const void* __restrict__ Wfc, const void* __restrict__ bfc,
    const void* __restrict__ Wr_for_sniff,
    void* __restrict__ io)
{
    const int f32 = sniff_fp32(Wr_for_sniff);
    const int lane = threadIdx.x & 63;
    const int wave = threadIdx.x >> 6;
    const int q = lane >> 4, l16 = lane & 15;
    const int m0 = blockIdx.x * 64 + wave * 16;
    const size_t aidx = (size_t)(m0 + l16) * 256 + q * 8;
    const size_t widx = (size_t)l16 * 256 + q * 8;
    f32x4 acc[16];
#pragma unroll
    for (int t = 0; t < 16; ++t) acc[t] = (f32x4){0, 0, 0, 0};
#pragma unroll 2
    for (int k0 = 0; k0 < 256; k0 += 32) {
        bf16x8 af = load8bf(io, aidx + k0, f32);
#pragma unroll
        for (int t = 0; t < 16; ++t) {
            bf16x8 bfg = load8bf(Wfc, widx + (size_t)t * 16 * 256 + k0, f32);
            acc[t] = MFMA16(af, bfg, acc[t]);
        }
    }
#pragma unroll
    for (int t = 0; t < 16; ++t) {
        const int col = t * 16 + l16;
        const float bv = load1f(bfc, col, f32);
#pragma unroll
        for (int r = 0; r < 4; ++r) {
            const size_t oidx = (size_t)(m0 + q * 4 + r) * 256 + col;
            float v = acc[t][r] + bv;
            if (f32) ((float*)io)[oidx] = v;
            else     ((u16*)io)[oidx] = f2bf(v);
        }
    }
}

// ---------------------------------------------------------------------------
extern "C" void kernel_launch(void* const* d_in, const int* in_sizes, int n_in,
                              void* d_out, int out_size, void* d_ws, size_t ws_size,
                              hipStream_t stream) {
    (void)in_sizes; (void)n_in; (void)out_size;
    const void* x   = d_in[0];
    const void* Wr  = d_in[1];
    const void* br  = d_in[2];
    const void* Wz  = d_in[3];
    const void* bz  = d_in[4];
    const void* Wh  = d_in[5];
    const void* bh  = d_in[6];
    const void* Wfc = d_in[7];
    const void* bfc = d_in[8];

    float* h_state = (float*)d_ws;                       // 64*256 fp32 = 64KB
    __half* gxc = (__half*)((char*)d_ws + 65536);        // [64][Sc][3][256] fp16

    // Chunk the time axis so the precomputed gates fit d_ws (Sc=1 -> 163KB).
    int lgSc = 11;
    while (lgSc > 0 &&
           (size_t)65536 + (((size_t)64 << lgSc) * 768 * 2) > ws_size) --lgSc;
    const int Sc = 1 << lgSc;

    for (int s0 = 0; s0 < 2048; s0 += Sc) {
        dim3 gpre(Sc, 12);
        gru_pre<<<gpre, 256, 0, stream>>>(x, Wr, Wz, Wh, br, bz, bh, gxc, s0, lgSc);
        gru_scan<<<64, 768, 0, stream>>>(gxc, Wr, Wz, Wh, h_state, d_out,
                                         s0, Sc, (s0 == 0) ? 1 : 0,
                                         (s0 + Sc == 2048) ? 1 : 0);
    }
    gru_proj<<<2048, 256, 0, stream>>>(Wfc, bfc, Wr, d_out);
}

// Round 4
// 4136.381 us; speedup vs baseline: 1.1260x; 1.1260x over previous
//
#include <hip/hip_runtime.h>
#include <hip/hip_bf16.h>
#include <hip/hip_fp16.h>

typedef unsigned short u16;
typedef unsigned int u32;
typedef __attribute__((ext_vector_type(8))) short bf16x8;
typedef __attribute__((ext_vector_type(4))) float f32x4;
typedef _Float16 __attribute__((ext_vector_type(2))) f16x2;

#define MFMA16(a, b, c) __builtin_amdgcn_mfma_f32_16x16x32_bf16((a), (b), (c), 0, 0, 0)

__device__ __forceinline__ float bflo(u32 u) { return __uint_as_float(u << 16); }
__device__ __forceinline__ float bfhi(u32 u) { return __uint_as_float(u & 0xffff0000u); }
__device__ __forceinline__ float bf1(u16 u) { return __uint_as_float(((u32)u) << 16); }
__device__ __forceinline__ u16 f2bf(float f) {
    __hip_bfloat16 b = __float2bfloat16(f);
    return __builtin_bit_cast(u16, b);
}

// ---------------------------------------------------------------------------
// Wave-uniform dtype sniff: 1 = fp32 inputs, 0 = bf16. (fp32 confirmed on HW
// in R3, but keep the guard — it costs ~nothing and is graph-safe.)
// ---------------------------------------------------------------------------
__device__ __forceinline__ int sniff_fp32(const void* Wr) {
    const uint4* p = (const uint4*)Wr;
    uint4 v = p[threadIdx.x & 15];
    u32 a[4] = {v.x, v.y, v.z, v.w};
    float m = 0.f;
#pragma unroll
    for (int i = 0; i < 4; ++i) {
        float lo = fabsf(bflo(a[i])), hi = fabsf(bfhi(a[i]));
        if (!(lo < 1e30f)) lo = 1e30f;
        if (!(hi < 1e30f)) hi = 1e30f;
        m = fmaxf(m, fmaxf(lo, hi));
    }
#pragma unroll
    for (int off = 32; off; off >>= 1) m = fmaxf(m, __shfl_xor(m, off, 64));
    return m > 100.f ? 1 : 0;
}

__device__ __forceinline__ bf16x8 load8bf(const void* base, size_t idx, int f32) {
    if (f32) {
        const float4* p = (const float4*)((const float*)base + idx);
        float4 v0 = p[0], v1 = p[1];
        bf16x8 r;
        r[0] = (short)f2bf(v0.x); r[1] = (short)f2bf(v0.y);
        r[2] = (short)f2bf(v0.z); r[3] = (short)f2bf(v0.w);
        r[4] = (short)f2bf(v1.x); r[5] = (short)f2bf(v1.y);
        r[6] = (short)f2bf(v1.z); r[7] = (short)f2bf(v1.w);
        return r;
    }
    return *(const bf16x8*)((const u16*)base + idx);
}

__device__ __forceinline__ void load8h(const void* base, size_t idx, int f32, f16x2* dst) {
    if (f32) {
        const float4* p = (const float4*)((const float*)base + idx);
        float4 v0 = p[0], v1 = p[1];
        dst[0] = f16x2{(_Float16)v0.x, (_Float16)v0.y};
        dst[1] = f16x2{(_Float16)v0.z, (_Float16)v0.w};
        dst[2] = f16x2{(_Float16)v1.x, (_Float16)v1.y};
        dst[3] = f16x2{(_Float16)v1.z, (_Float16)v1.w};
    } else {
        uint4 v = *(const uint4*)((const u16*)base + idx);
        dst[0] = f16x2{(_Float16)bflo(v.x), (_Float16)bfhi(v.x)};
        dst[1] = f16x2{(_Float16)bflo(v.y), (_Float16)bfhi(v.y)};
        dst[2] = f16x2{(_Float16)bflo(v.z), (_Float16)bfhi(v.z)};
        dst[3] = f16x2{(_Float16)bflo(v.w), (_Float16)bfhi(v.w)};
    }
}

__device__ __forceinline__ float load1f(const void* base, size_t idx, int f32) {
    return f32 ? ((const float*)base)[idx] : bf1(((const u16*)base)[idx]);
}

// ---------------------------------------------------------------------------
// Precompute v2: gx[m][g][n] = x_row(m) . W_g[n][0:256] + b_g[n]  (fp16).
// One block per 64 chunk-rows; A-tile staged ONCE in LDS as bf16 (kills the
// 12x re-read of x that round-3 did). Each wave computes 3 of the 12
// (gate, 64-col) groups: 64 rows x 64 cols, 16 acc tiles, B from L2.
// ---------------------------------------------------------------------------
__global__ __launch_bounds__(256, 2) void gru_pre(
    const void* __restrict__ x,
    const void* __restrict__ Wr, const void* __restrict__ Wz, const void* __restrict__ Wh,
    const void* __restrict__ br, const void* __restrict__ bz, const void* __restrict__ bh,
    __half* __restrict__ gxc, int s0, int lgSc)
{
    const int f32 = sniff_fp32(Wr);
    const int tid = threadIdx.x;
    const int R0 = blockIdx.x * 64;

    __shared__ __align__(16) u16 As[64][264];   // bf16, +8 pad

    // ---- stage A: thread t -> row i = t>>2, k-quarter (t&3)*64 ----
    {
        const int i = tid >> 2;
        const int kq = (tid & 3) * 64;
        const int m = R0 + i;
        const int b = m >> lgSc;
        const int sl = m & ((1 << lgSc) - 1);
        const size_t xbase = ((size_t)(b * 2048 + s0 + sl)) * 256 + kq;
        u16* dst = &As[i][kq];
        if (f32) {
            const float4* p = (const float4*)((const float*)x + xbase);
#pragma unroll
            for (int j = 0; j < 8; ++j) {
                float4 v0 = p[2 * j], v1 = p[2 * j + 1];
                uint4 o;
                o.x = ((u32)f2bf(v0.y) << 16) | f2bf(v0.x);
                o.y = ((u32)f2bf(v0.w) << 16) | f2bf(v0.z);
                o.z = ((u32)f2bf(v1.y) << 16) | f2bf(v1.x);
                o.w = ((u32)f2bf(v1.w) << 16) | f2bf(v1.z);
                *(uint4*)(dst + j * 8) = o;
            }
        } else {
            const uint4* p = (const uint4*)((const u16*)x + xbase);
#pragma unroll
            for (int j = 0; j < 8; ++j) *(uint4*)(dst + j * 8) = p[j];
        }
    }
    __syncthreads();

    // ---- compute: wave wv handles groups gi = wv*3 + {0,1,2} ----
    const int wv = tid >> 6;
    const int lane = tid & 63;
    const int q = lane >> 4, l16 = lane & 15;

    for (int j = 0; j < 3; ++j) {
        const int gi = wv * 3 + j;            // 0..11
        const int g = gi >> 2;
        const int col0 = (gi & 3) * 64;
        const void* W    = (g == 0) ? Wr : ((g == 1) ? Wz : Wh);
        const void* bias = (g == 0) ? br : ((g == 1) ? bz : bh);
        const size_t wbase = (size_t)(col0 + l16) * 512 + q * 8;

        f32x4 acc[4][4];
#pragma unroll
        for (int mt = 0; mt < 4; ++mt)
#pragma unroll
            for (int nt = 0; nt < 4; ++nt) acc[mt][nt] = (f32x4){0, 0, 0, 0};

#pragma unroll
        for (int k0 = 0; k0 < 256; k0 += 32) {
            bf16x8 bfr[4];
#pragma unroll
            for (int nt = 0; nt < 4; ++nt)
                bfr[nt] = load8bf(W, wbase + (size_t)nt * 16 * 512 + k0, f32);
#pragma unroll
            for (int mt = 0; mt < 4; ++mt) {
                bf16x8 af = *(const bf16x8*)&As[mt * 16 + l16][k0 + q * 8];
#pragma unroll
                for (int nt = 0; nt < 4; ++nt)
                    acc[mt][nt] = MFMA16(af, bfr[nt], acc[mt][nt]);
            }
        }
        // D: col = l16, row = q*4 + r
#pragma unroll
        for (int nt = 0; nt < 4; ++nt) {
            const int col = col0 + nt * 16 + l16;
            const float bv = load1f(bias, col, f32);
#pragma unroll
            for (int mt = 0; mt < 4; ++mt)
#pragma unroll
                for (int r = 0; r < 4; ++r) {
                    const int row = R0 + mt * 16 + q * 4 + r;
                    gxc[(size_t)row * 768 + g * 256 + col] =
                        __float2half(acc[mt][nt][r] + bv);
                }
        }
    }
}

// ---------------------------------------------------------------------------
// 256-wide dot: fp16 pairs, fp32 accumulate (v_dot2_f32_f16). w in registers,
// hp in LDS (same-address wave broadcast, conflict-free).
// ---------------------------------------------------------------------------
__device__ __forceinline__ float dot256(const f16x2* w, const _Float16* hp) {
    const uint4* hp4 = (const uint4*)hp;
    float a0 = 0.f, a1 = 0.f, a2 = 0.f, a3 = 0.f;
#pragma unroll
    for (int c = 0; c < 32; ++c) {
        uint4 hv = hp4[c];
        f16x2 h0 = __builtin_bit_cast(f16x2, hv.x);
        f16x2 h1 = __builtin_bit_cast(f16x2, hv.y);
        f16x2 h2 = __builtin_bit_cast(f16x2, hv.z);
        f16x2 h3 = __builtin_bit_cast(f16x2, hv.w);
#if __has_builtin(__builtin_amdgcn_fdot2)
        a0 = __builtin_amdgcn_fdot2(w[c * 4 + 0], h0, a0, false);
        a1 = __builtin_amdgcn_fdot2(w[c * 4 + 1], h1, a1, false);
        a2 = __builtin_amdgcn_fdot2(w[c * 4 + 2], h2, a2, false);
        a3 = __builtin_amdgcn_fdot2(w[c * 4 + 3], h3, a3, false);
#else
        a0 += (float)w[c*4+0][0] * (float)h0[0] + (float)w[c*4+0][1] * (float)h0[1];
        a1 += (float)w[c*4+1][0] * (float)h1[0] + (float)w[c*4+1][1] * (float)h1[1];
        a2 += (float)w[c*4+2][0] * (float)h2[0] + (float)w[c*4+2][1] * (float)h2[1];
        a3 += (float)w[c*4+3][0] * (float)h3[0] + (float)w[c*4+3][1] * (float)h3[1];
#endif
    }
    return (a0 + a1) + (a2 + a3);
}

// ---------------------------------------------------------------------------
// Sequential scan: one workgroup per batch, 768 threads, thread (g,n) owns
// W_g[n][256:512] in 128 f16x2 REGISTERS.
// __launch_bounds__(768, 3): 3 waves/EU -> VGPR cap 170 (round 3's cap of 84
// spilled the weight array to scratch -> 4000 cyc/step; this is THE fix).
// ---------------------------------------------------------------------------
__global__ __launch_bounds__(768, 3) void gru_scan(
    const __half* __restrict__ gxc,
    const void* __restrict__ Wr, const void* __restrict__ Wz, const void* __restrict__ Wh,
    float* __restrict__ h_state,
    void* __restrict__ outbase,            // d_out; h_last at element 33554432
    int s0, int Sc, int first, int last)
{
    const int f32 = sniff_fp32(Wr);
    const int b = blockIdx.x;
    const int tid = threadIdx.x;
    const int g = tid >> 8;   // 0=r, 1=z, 2=h  (wave-uniform)
    const int n = tid & 255;

    __shared__ __align__(16) _Float16 h_h[256];
    __shared__ __align__(16) _Float16 rh_h[256];
    __shared__ float h_f[256];
    __shared__ float z_f[256];

    const void* W = (g == 0) ? Wr : ((g == 1) ? Wz : Wh);
    f16x2 w[128];
#pragma unroll
    for (int c = 0; c < 32; ++c)
        load8h(W, (size_t)n * 512 + 256 + c * 8, f32, &w[c * 4]);

    if (g == 0) {
        float h0 = first ? 0.0f : h_state[b * 256 + n];
        h_f[n] = h0;
        h_h[n] = (_Float16)h0;
    }
    __syncthreads();

    const __half* gxp = gxc + (size_t)b * Sc * 768 + g * 256 + n;
    __half cur = gxp[0];

    for (int s = 0; s < Sc; ++s) {
        __half nxt = (s + 1 < Sc) ? gxp[(size_t)(s + 1) * 768] : cur;

        if (g < 2) {  // phase 1: r and z
            float acc = dot256(w, h_h);
            float pre = acc + __half2float(cur);
            pre = fminf(fmaxf(pre, -30.0f), 30.0f);
            float val = __fdividef(1.0f, 1.0f + __expf(-pre));
            if (g == 0) rh_h[n] = (_Float16)(val * h_f[n]);
            else        z_f[n] = val;
        }
        __syncthreads();

        if (g == 2) {  // phase 2: candidate + update
            float acc = dot256(w, rh_h);
            float pre = acc + __half2float(cur);
            pre = fminf(fmaxf(pre, -15.0f), 15.0f);
            float e = __expf(2.0f * pre);
            float ht = __fdividef(e - 1.0f, e + 1.0f);
            float hold = h_f[n];
            float zz = z_f[n];
            float hn = hold + zz * (ht - hold);
            h_f[n] = hn;
            h_h[n] = (_Float16)hn;
            const size_t oidx = (size_t)(b * 2048 + s0 + s) * 256 + n;
            if (f32) ((float*)outbase)[oidx] = hn;
            else     ((u16*)outbase)[oidx] = f2bf(hn);
            if (s == Sc - 1) {
                h_state[b * 256 + n] = hn;
                if (last) {
                    const size_t lidx = (size_t)33554432 + b * 256 + n;
                    if (f32) ((float*)outbase)[lidx] = hn;
                    else     ((u16*)outbase)[lidx] = f2bf(hn);
                }
            }
        }
        __syncthreads();
        cur = nxt;
    }
}

// ---------------------------------------------------------------------------
// Output projection IN-PLACE in d_out. Each wave reads exactly the 16 rows it
// later overwrites (loads precede stores in its program order; waves own
// disjoint rows) -> race-free.
// ---------------------------------------------------------------------------
__global__ __launch_bounds__(256) void gru_proj(
    const void* __restrict__ Wfc, const void* __restrict__ bfc,
    const void* __restrict__ Wr_for_sniff,
    void* __restrict__ io)
{
    const int f32 = sniff_fp32(Wr_for_sniff);
    const int lane = threadIdx.x & 63;
    const int wave = threadIdx.x >> 6;
    const int q = lane >> 4, l16 = lane & 15;
    const int m0 = blockIdx.x * 64 + wave * 16;
    const size_t aidx = (size_t)(m0 + l16) * 256 + q * 8;
    const size_t widx = (size_t)l16 * 256 + q * 8;
    f32x4 acc[16];
#pragma unroll
    for (int t = 0; t < 16; ++t) acc[t] = (f32x4){0, 0, 0, 0};
#pragma unroll 2
    for (int k0 = 0; k0 < 256; k0 += 32) {
        bf16x8 af = load8bf(io, aidx + k0, f32);
#pragma unroll
        for (int t = 0; t < 16; ++t) {
            bf16x8 bfg = load8bf(Wfc, widx + (size_t)t * 16 * 256 + k0, f32);
            acc[t] = MFMA16(af, bfg, acc[t]);
        }
    }
#pragma unroll
    for (int t = 0; t < 16; ++t) {
        const int col = t * 16 + l16;
        const float bv = load1f(bfc, col, f32);
#pragma unroll
        for (int r = 0; r < 4; ++r) {
            const size_t oidx = (size_t)(m0 + q * 4 + r) * 256 + col;
            float v = acc[t][r] + bv;
            if (f32) ((float*)io)[oidx] = v;
            else     ((u16*)io)[oidx] = f2bf(v);
        }
    }
}

// ---------------------------------------------------------------------------
extern "C" void kernel_launch(void* const* d_in, const int* in_sizes, int n_in,
                              void* d_out, int out_size, void* d_ws, size_t ws_size,
                              hipStream_t stream) {
    (void)in_sizes; (void)n_in; (void)out_size;
    const void* x   = d_in[0];
    const void* Wr  = d_in[1];
    const void* br  = d_in[2];
    const void* Wz  = d_in[3];
    const void* bz  = d_in[4];
    const void* Wh  = d_in[5];
    const void* bh  = d_in[6];
    const void* Wfc = d_in[7];
    const void* bfc = d_in[8];

    float* h_state = (float*)d_ws;                       // 64*256 fp32 = 64KB
    __half* gxc = (__half*)((char*)d_ws + 65536);        // [64][Sc][3][256] fp16

    // Chunk the time axis so the precomputed gates fit d_ws (Sc=1 -> 163KB).
    int lgSc = 11;
    while (lgSc > 0 &&
           (size_t)65536 + (((size_t)64 << lgSc) * 768 * 2) > ws_size) --lgSc;
    const int Sc = 1 << lgSc;

    for (int s0 = 0; s0 < 2048; s0 += Sc) {
        gru_pre<<<Sc, 256, 0, stream>>>(x, Wr, Wz, Wh, br, bz, bh, gxc, s0, lgSc);
        gru_scan<<<64, 768, 0, stream>>>(gxc, Wr, Wz, Wh, h_state, d_out,
                                         s0, Sc, (s0 == 0) ? 1 : 0,
                                         (s0 + Sc == 2048) ? 1 : 0);
    }
    gru_proj<<<2048, 256, 0, stream>>>(Wfc, bfc, Wr, d_out);
}